// Round 9
// baseline (303.316 us; speedup 1.0000x reference)
//
#include <hip/hip_runtime.h>
#include <cfloat>
#include <math.h>

#define NPTS   5000
#define BATCH  2
#define DIM    128
#define NBINS  10
#define BINSZ  500
#define TOPK   5
#define ROTCOLS 100   // rotations stored [128, 100]; we use first NBINS/2 = 5

// ---------------- Kernel A: bin assignment + squared norms (fp64 acc) -----
// Stays fp64: a single argmax flip vs the np-f64 reference permutes whole
// bins (catastrophic).
#define KB_PTS 64
#define KB_STR 129
__global__ void k_bins(const float* __restrict__ pts, const float* __restrict__ rot,
                       int* __restrict__ bin_idx, double* __restrict__ na) {
    __shared__ float P[KB_PTS * KB_STR];
    __shared__ float rotL[DIM * 5];
    int tid = threadIdx.x;
    for (int f = tid; f < DIM * 5; f += 256)
        rotL[f] = rot[(f / 5) * ROTCOLS + (f % 5)];

    int p0  = blockIdx.x * KB_PTS;
    int npb = min(KB_PTS, BATCH * NPTS - p0);

    for (int f = tid; f < npb * DIM; f += 256) {
        int r = f >> 7, d = f & 127;
        P[r * KB_STR + d] = pts[(size_t)(p0 + r) * DIM + d];
    }
    __syncthreads();

    int p = tid >> 2;    // point within block
    int s = tid & 3;     // dim quarter
    double acc[5] = {0., 0., 0., 0., 0.};
    double sq = 0.;
    const float* row = &P[p * KB_STR + s * 32];
    for (int j = 0; j < 32; ++j) {
        double v = (double)row[j];
        sq += v * v;
        int d = s * 32 + j;
#pragma unroll
        for (int h = 0; h < 5; ++h) acc[h] += v * (double)rotL[d * 5 + h];
    }
#pragma unroll
    for (int m = 1; m < 4; m <<= 1) {
#pragma unroll
        for (int h = 0; h < 5; ++h) acc[h] += __shfl_xor(acc[h], m, 4);
        sq += __shfl_xor(sq, m, 4);
    }
    if (s == 0 && p < npb) {
        double best = acc[0]; int bc = 0;
#pragma unroll
        for (int c = 1; c < NBINS; ++c) {
            double v = (c < 5) ? acc[c] : -acc[c - 5];
            if (v > best) { best = v; bc = c; }
        }
        bin_idx[p0 + p] = bc;
        na[p0 + p] = sq;
    }
}

// ---------------- Kernel B: stable counting sort (== stable argsort) ------
__global__ void k_sort(const int* __restrict__ bin_idx, int* __restrict__ order) {
    const int b = blockIdx.x;
    const int t = threadIdx.x;               // 256 threads
    const int NPT = (NPTS + 255) / 256;      // 20
    int start = t * NPT;
    int end   = min(NPTS, start + NPT);

    int cnt[NBINS];
#pragma unroll
    for (int c = 0; c < NBINS; ++c) cnt[c] = 0;
    for (int i = start; i < end; ++i) {
        int c = bin_idx[b * NPTS + i];
#pragma unroll
        for (int k = 0; k < NBINS; ++k) cnt[k] += (c == k);
    }

    __shared__ int hist[NBINS * 256];
#pragma unroll
    for (int c = 0; c < NBINS; ++c) hist[c * 256 + t] = cnt[c];
    __syncthreads();

    int base = t * NBINS;
    int s = 0;
#pragma unroll
    for (int k = 0; k < NBINS; ++k) s += hist[base + k];
    __shared__ int scan[256];
    scan[t] = s;
    __syncthreads();
    for (int off = 1; off < 256; off <<= 1) {
        int v = (t >= off) ? scan[t - off] : 0;
        __syncthreads();
        scan[t] += v;
        __syncthreads();
    }
    int run = scan[t] - s;
#pragma unroll
    for (int k = 0; k < NBINS; ++k) { int h = hist[base + k]; hist[base + k] = run; run += h; }
    __syncthreads();

    int ofs[NBINS];
#pragma unroll
    for (int c = 0; c < NBINS; ++c) ofs[c] = hist[c * 256 + t];
    for (int i = start; i < end; ++i) {
        int c = bin_idx[b * NPTS + i];
        int pos = 0;
#pragma unroll
        for (int k = 0; k < NBINS; ++k) {
            if (c == k) pos = ofs[k];
            ofs[k] += (c == k);
        }
        order[b * NPTS + pos] = i;
    }
}

// -- Kernel C: all-f64-LDS gram + async-staged tiles + top-5 + zero --------
// Evidence ledger:
//  * f64 MFMA abandoned (R0-R2): probe outputs match NO layout family on
//    gfx950 -> unusable. Do not revisit without external proof.
//  * R3: -33% LDS reads = zero time change => not LDS-throughput-bound.
//  * R4: f32 gram + 8-wide rank: VALU busy unchanged, duration 2x. Gram
//    FLOPs are NOT dominant; wide-candidate-state is a trap.
//  * R5: zero-fill split out = k_chunks unchanged => embedded zeroing free.
//  * R6: occupancy 22->53% (more blocks) = WORSE (+restage). Keep 640 blocks.
//  * R7: ordAll-in-LDS + T14 reg-prefetch staging = 123 -> ~114us (win).
//  * R8 (this): B-operand was f32->f64 converted at EVERY use (2048 cvt/
//    thread ~ 30% of VALU). Stage colP as f64 (cvt once at write: 8x less),
//    CTILE 64->32 to keep LDS at 52.3KB / 3 blocks-CU, SAME 640 blocks.
//    Gram term order / selection / merge bit-identical to R3/R7.
//  * All selection state static-indexed (scratch trap).
#define RT    16
#define NRT   32
#define CTILE 32
#define RSTRD 130      // rowPd stride in doubles (1040 B rows, 16B-aligned)
#define CSTRD 130      // colPd stride in doubles
#define NCT   16       // 500 cols -> 16 tiles of 32 (last = 20)
#define ROWQ  (NPTS/4)

// issue next tile's staging loads into static registers (ordAll must be synced)
#define ISSUE_TILE(CT)                                                        \
    {                                                                         \
        int c0_ = (CT) * CTILE;                                               \
        int jb_ = tid >> 5;                                                   \
        int q4_ = (tid & 31) * 4;                                             \
        p0 = *(const float4*)(ptsB + (size_t)ordAll[min(c0_ + jb_ +  0, BINSZ - 1)] * DIM + q4_); \
        p1 = *(const float4*)(ptsB + (size_t)ordAll[min(c0_ + jb_ +  8, BINSZ - 1)] * DIM + q4_); \
        p2 = *(const float4*)(ptsB + (size_t)ordAll[min(c0_ + jb_ + 16, BINSZ - 1)] * DIM + q4_); \
        p3 = *(const float4*)(ptsB + (size_t)ordAll[min(c0_ + jb_ + 24, BINSZ - 1)] * DIM + q4_); \
        naCp = na[(size_t)b * NPTS + ordAll[min(c0_ + (tid & 31), BINSZ - 1)]]; \
    }

// convert one prefetched float4 to doubles and store to colPd row (jb+OFF)
#define WRITE_COL(P, OFF)                                                     \
    {                                                                         \
        double2 dlo_, dhi_;                                                   \
        dlo_.x = (double)P.x; dlo_.y = (double)P.y;                           \
        dhi_.x = (double)P.z; dhi_.y = (double)P.w;                           \
        *(double2*)(&colPd[(jb + OFF) * CSTRD + q4 + 0]) = dlo_;              \
        *(double2*)(&colPd[(jb + OFF) * CSTRD + q4 + 2]) = dhi_;              \
    }

__launch_bounds__(256, 3)
__global__ void k_chunks(const float* __restrict__ pts, const double* __restrict__ na,
                         const int* __restrict__ order, float* __restrict__ out) {
    __shared__ double rowPd[RT * RSTRD];       // 16640 B
    __shared__ double colPd[CTILE * CSTRD];    // 33280 B
    __shared__ double naC[CTILE];              // 256 B
    __shared__ double naRs[RT];                // 128 B
    __shared__ int    ordR[RT];                // 64 B
    __shared__ int    ordAll[BINSZ];           // 2000 B -> 52.3 KB, 3 blocks/CU

    int blk   = blockIdx.x;
    int rt    = blk & (NRT - 1);
    int chunk = blk >> 5;          // 0..19
    int b     = chunk / NBINS;
    int c     = chunk % NBINS;
    int tid   = threadIdx.x;
    int row0  = rt * RT;
    int rowCount = min(RT, BINSZ - row0);   // 16, except last tile: 4

    const int*   ordBase = order + b * NPTS + c * BINSZ;
    const float* ptsB    = pts + (size_t)b * NPTS * DIM;

    // cache this chunk's order slice (kills the per-tile dependent ord loads)
    for (int f = tid; f < BINSZ; f += 256) ordAll[f] = ordBase[f];

    // stage row points as doubles (gathered via order; cvt once per element)
    for (int f = tid; f < rowCount * (DIM / 4); f += 256) {
        int r = f >> 5;
        int q = f & 31;
        int g = ordBase[row0 + r];
        float4 v = *(const float4*)(ptsB + (size_t)g * DIM + q * 4);
        double2 d01; d01.x = (double)v.x; d01.y = (double)v.y;
        double2 d23; d23.x = (double)v.z; d23.y = (double)v.w;
        *(double2*)(&rowPd[r * RSTRD + q * 4 + 0]) = d01;
        *(double2*)(&rowPd[r * RSTRD + q * 4 + 2]) = d23;
    }
    if (tid < rowCount) {
        int g = ordBase[row0 + tid];
        ordR[tid] = g;
        naRs[tid] = na[b * NPTS + g];
    }
    __syncthreads();   // ordAll + rows ready

    int cg  = tid & 15;         // col group: owns col cg (ks=0) / cg+16 (ks=1)
    int ks  = (tid >> 4) & 1;   // k-half: dims [64ks, 64ks+64)
    int rg  = tid >> 5;         // 0..7: rows rg, rg+8
    int cgm = tid & 31;         // merge-lane id within half-wave
    const int q0 = ks * 64;

    double naRr0 = (rg     < rowCount) ? naRs[rg]     : 0.;
    double naRr1 = (rg + 8 < rowCount) ? naRs[rg + 8] : 0.;

    // selection key: clamped squared distance (smaller = better); bottom-5,
    // strict < with in-order arrival == (key asc, idx asc), matches ref.
    double tv[2][TOPK];
    int    tl[2][TOPK];
#pragma unroll
    for (int ii = 0; ii < 2; ++ii)
#pragma unroll
        for (int k = 0; k < TOPK; ++k) { tv[ii][k] = DBL_MAX; tl[ii][k] = 0x7fffffff; }

    const int totalZ = rowCount * ROWQ;

    // prefetch tile 0 into registers
    float4 p0, p1, p2, p3;
    double naCp;
    ISSUE_TILE(0);

    for (int ct = 0; ct < NCT; ++ct) {
        int col0T = ct * CTILE;
        int colCount = min(CTILE, BINSZ - col0T);   // 32, last tile: 20
        __syncthreads();   // prev tile's readers done before restage

        // write phase: regs (loaded last iteration) -> LDS, cvt once here
        {
            int jb = tid >> 5;
            int q4 = (tid & 31) * 4;
            WRITE_COL(p0,  0);
            WRITE_COL(p1,  8);
            WRITE_COL(p2, 16);
            WRITE_COL(p3, 24);
            if (tid < CTILE) naC[tid] = naCp;
        }
        __syncthreads();

        // issue next tile's loads now; they complete under this tile's gram
        if (ct + 1 < NCT) ISSUE_TILE(ct + 1);

        // zero-fill slice ct: stores drain during this tile's gram compute
        {
            float4 z = make_float4(0.f, 0.f, 0.f, 0.f);
            int z0 = (ct * totalZ) / NCT, z1 = ((ct + 1) * totalZ) / NCT;
            for (int f = z0 + tid; f < z1; f += 256) {
                int r = f / ROWQ;
                int q = f - r * ROWQ;
                float* outRow = out + ((size_t)b * NPTS + ordR[r]) * NPTS;
                *(float4*)(outRow + 4 * q) = z;
            }
        }

        // gram: rows {rg, rg+8} x cols {cg, cg+16}, dims [q0, q0+64)
        double acc00 = 0., acc01 = 0.;   // row rg   x cols cg, cg+16
        double acc10 = 0., acc11 = 0.;   // row rg+8 x cols cg, cg+16

        for (int q = 0; q < 64; q += 4) {
            const int qq = q0 + q;
            double2 a0lo = *(const double2*)(&rowPd[rg * RSTRD + qq + 0]);
            double2 a0hi = *(const double2*)(&rowPd[rg * RSTRD + qq + 2]);
            double2 a1lo = *(const double2*)(&rowPd[(rg + 8) * RSTRD + qq + 0]);
            double2 a1hi = *(const double2*)(&rowPd[(rg + 8) * RSTRD + qq + 2]);
            double2 b0lo = *(const double2*)(&colPd[cg * CSTRD + qq + 0]);
            double2 b0hi = *(const double2*)(&colPd[cg * CSTRD + qq + 2]);
            double2 b1lo = *(const double2*)(&colPd[(cg + 16) * CSTRD + qq + 0]);
            double2 b1hi = *(const double2*)(&colPd[(cg + 16) * CSTRD + qq + 2]);
            acc00 += a0lo.x * b0lo.x + a0lo.y * b0lo.y + a0hi.x * b0hi.x + a0hi.y * b0hi.y;
            acc01 += a0lo.x * b1lo.x + a0lo.y * b1lo.y + a0hi.x * b1hi.x + a0hi.y * b1hi.y;
            acc10 += a1lo.x * b0lo.x + a1lo.y * b0lo.y + a1hi.x * b0hi.x + a1hi.y * b0hi.y;
            acc11 += a1lo.x * b1lo.x + a1lo.y * b1lo.y + a1hi.x * b1hi.x + a1hi.y * b1hi.y;
        }

        // combine k-halves: partner lane = lane^16 (same cg, same rg)
        acc00 += __shfl_xor(acc00, 16, 64);
        acc01 += __shfl_xor(acc01, 16, 64);
        acc10 += __shfl_xor(acc10, 16, 64);
        acc11 += __shfl_xor(acc11, 16, 64);

        // selection ownership: ks=0 -> col cg; ks=1 -> col cg+16
        double sel0 = ks ? acc01 : acc00;   // row rg
        double sel1 = ks ? acc11 : acc10;   // row rg+8
        int    col  = cg + (ks ? 16 : 0);

        if (col < colCount) {
            int    cl = col0T + col;
            double nc = naC[col];
            double cv0 = fmax(naRr0 + nc - 2. * sel0, 1e-6);
            double cv1 = fmax(naRr1 + nc - 2. * sel1, 1e-6);
            int cl0 = cl, cl1 = cl;
#pragma unroll
            for (int k = 0; k < TOPK; ++k) {   // strict <: equal keeps earlier idx
                bool lt0 = (cv0 < tv[0][k]);
                double ov0 = tv[0][k]; int ol0 = tl[0][k];
                if (lt0) { tv[0][k] = cv0; tl[0][k] = cl0; cv0 = ov0; cl0 = ol0; }
                bool lt1 = (cv1 < tv[1][k]);
                double ov1 = tv[1][k]; int ol1 = tl[1][k];
                if (lt1) { tv[1][k] = cv1; tl[1][k] = cl1; cv1 = ov1; cl1 = ol1; }
            }
        }
    }

    // merge across the 32 threads of each half-wave (all share rows rg, rg+8;
    // they own disjoint col sets covering 0..499)
#pragma unroll
    for (int m = 1; m < 32; m <<= 1) {
#pragma unroll
        for (int ii = 0; ii < 2; ++ii) {
            double rv[TOPK]; int rl[TOPK];
#pragma unroll
            for (int k = 0; k < TOPK; ++k) {
                rv[k] = __shfl_xor(tv[ii][k], m, 32);
                rl[k] = __shfl_xor(tl[ii][k], m, 32);
            }
#pragma unroll
            for (int k = 0; k < TOPK; ++k) {
                double cv = rv[k]; int cl = rl[k];
#pragma unroll
                for (int s = 0; s < TOPK; ++s) {   // (key asc, idx asc) total order
                    bool better = (cv < tv[ii][s]) || (cv == tv[ii][s] && cl < tl[ii][s]);
                    double ov = tv[ii][s]; int ol = tl[ii][s];
                    if (better) { tv[ii][s] = cv; tl[ii][s] = cl; cv = ov; cl = ol; }
                }
            }
        }
    }

    __syncthreads();   // drain last zero slice before value scatter

    // scatter: lane cgm==0 of each half-wave writes 2 rows x 5 values
    if (cgm == 0) {
#pragma unroll
        for (int ii = 0; ii < 2; ++ii) {
            int r = rg + 8 * ii;
            if (r < rowCount) {
                int src = ordR[r];
                float* outRow = out + ((size_t)b * NPTS + src) * NPTS;
#pragma unroll
                for (int k = 0; k < TOPK; ++k) {
                    double dist = sqrt(tv[ii][k]);     // tv already clamped
                    double dm   = exp(-0.1 * dist);
                    int dst = ordAll[tl[ii][k]];       // chunk-local -> global
                    outRow[dst] = (float)dm;
                }
            }
        }
    }
}

// ---------------- launch ----------------
extern "C" void kernel_launch(void* const* d_in, const int* in_sizes, int n_in,
                              void* d_out, int out_size, void* d_ws, size_t ws_size,
                              hipStream_t stream) {
    const float* pts = (const float*)d_in[0];   // [2,5000,128]
    const float* rot = (const float*)d_in[1];   // [128,100]
    float* out = (float*)d_out;                 // [2,5000,5000]

    double* na      = (double*)d_ws;                                    // 80000 B
    int*    bin_idx = (int*)((char*)d_ws + 80000);                      // 40000 B
    int*    order   = (int*)((char*)d_ws + 120000);                     // 40000 B

    k_bins<<<(BATCH * NPTS + KB_PTS - 1) / KB_PTS, 256, 0, stream>>>(pts, rot, bin_idx, na);
    k_sort<<<BATCH, 256, 0, stream>>>(bin_idx, order);
    k_chunks<<<BATCH * NBINS * NRT, 256, 0, stream>>>(pts, na, order, out);
}

// Round 10
// 291.329 us; speedup vs baseline: 1.0411x; 1.0411x over previous
//
#include <hip/hip_runtime.h>
#include <cfloat>
#include <math.h>

#define NPTS   5000
#define BATCH  2
#define DIM    128
#define NBINS  10
#define BINSZ  500
#define TOPK   5
#define ROTCOLS 100   // rotations stored [128, 100]; we use first NBINS/2 = 5

// ---------------- Kernel A: bin assignment + squared norms (fp64 acc) -----
// Stays fp64: a single argmax flip vs the np-f64 reference permutes whole
// bins (catastrophic).
#define KB_PTS 64
#define KB_STR 129
__global__ void k_bins(const float* __restrict__ pts, const float* __restrict__ rot,
                       int* __restrict__ bin_idx, double* __restrict__ na) {
    __shared__ float P[KB_PTS * KB_STR];
    __shared__ float rotL[DIM * 5];
    int tid = threadIdx.x;
    for (int f = tid; f < DIM * 5; f += 256)
        rotL[f] = rot[(f / 5) * ROTCOLS + (f % 5)];

    int p0  = blockIdx.x * KB_PTS;
    int npb = min(KB_PTS, BATCH * NPTS - p0);

    for (int f = tid; f < npb * DIM; f += 256) {
        int r = f >> 7, d = f & 127;
        P[r * KB_STR + d] = pts[(size_t)(p0 + r) * DIM + d];
    }
    __syncthreads();

    int p = tid >> 2;    // point within block
    int s = tid & 3;     // dim quarter
    double acc[5] = {0., 0., 0., 0., 0.};
    double sq = 0.;
    const float* row = &P[p * KB_STR + s * 32];
    for (int j = 0; j < 32; ++j) {
        double v = (double)row[j];
        sq += v * v;
        int d = s * 32 + j;
#pragma unroll
        for (int h = 0; h < 5; ++h) acc[h] += v * (double)rotL[d * 5 + h];
    }
#pragma unroll
    for (int m = 1; m < 4; m <<= 1) {
#pragma unroll
        for (int h = 0; h < 5; ++h) acc[h] += __shfl_xor(acc[h], m, 4);
        sq += __shfl_xor(sq, m, 4);
    }
    if (s == 0 && p < npb) {
        double best = acc[0]; int bc = 0;
#pragma unroll
        for (int c = 1; c < NBINS; ++c) {
            double v = (c < 5) ? acc[c] : -acc[c - 5];
            if (v > best) { best = v; bc = c; }
        }
        bin_idx[p0 + p] = bc;
        na[p0 + p] = sq;
    }
}

// ---------------- Kernel B: stable counting sort (== stable argsort) ------
__global__ void k_sort(const int* __restrict__ bin_idx, int* __restrict__ order) {
    const int b = blockIdx.x;
    const int t = threadIdx.x;               // 256 threads
    const int NPT = (NPTS + 255) / 256;      // 20
    int start = t * NPT;
    int end   = min(NPTS, start + NPT);

    int cnt[NBINS];
#pragma unroll
    for (int c = 0; c < NBINS; ++c) cnt[c] = 0;
    for (int i = start; i < end; ++i) {
        int c = bin_idx[b * NPTS + i];
#pragma unroll
        for (int k = 0; k < NBINS; ++k) cnt[k] += (c == k);
    }

    __shared__ int hist[NBINS * 256];
#pragma unroll
    for (int c = 0; c < NBINS; ++c) hist[c * 256 + t] = cnt[c];
    __syncthreads();

    int base = t * NBINS;
    int s = 0;
#pragma unroll
    for (int k = 0; k < NBINS; ++k) s += hist[base + k];
    __shared__ int scan[256];
    scan[t] = s;
    __syncthreads();
    for (int off = 1; off < 256; off <<= 1) {
        int v = (t >= off) ? scan[t - off] : 0;
        __syncthreads();
        scan[t] += v;
        __syncthreads();
    }
    int run = scan[t] - s;
#pragma unroll
    for (int k = 0; k < NBINS; ++k) { int h = hist[base + k]; hist[base + k] = run; run += h; }
    __syncthreads();

    int ofs[NBINS];
#pragma unroll
    for (int c = 0; c < NBINS; ++c) ofs[c] = hist[c * 256 + t];
    for (int i = start; i < end; ++i) {
        int c = bin_idx[b * NPTS + i];
        int pos = 0;
#pragma unroll
        for (int k = 0; k < NBINS; ++k) {
            if (c == k) pos = ofs[k];
            ofs[k] += (c == k);
        }
        order[b * NPTS + pos] = i;
    }
}

// -- Kernel C: k-split 2x4 f64 gram + async-staged tiles + top-5 ----------
// Evidence ledger:
//  * f64 MFMA abandoned (R0-R2): probe outputs match NO layout family on
//    gfx950 -> unusable. Do not revisit without external proof.
//  * R3: -33% LDS reads = zero time change => not LDS-throughput-bound.
//  * R4: f32 gram + 8-wide rank: VALU busy unchanged, duration 2x. Gram
//    FLOPs are NOT dominant; wide-candidate-state is a trap.
//  * R5: zero-fill split out = k_chunks unchanged => embedded zeroing free.
//  * R6: occupancy 22->53% (more blocks) = WORSE (+restage). Keep 640 blocks.
//  * R7: ordAll-in-LDS + T14 reg-prefetch staging = 123 -> ~114us (win).
//  * R8: f64 colP staging cut VALU busy 56->47us BUT NCT 8->16 doubled
//    barriers: duration +19us. Per-tile barrier overhead ~2.4us dominates.
//    KEEP NCT=8 / CTILE=64 / f32 colP.
//  * R9 (this): dropped the embedded 197MB zero-fill -- the HARNESS memsets
//    out to 0 before every launch (verified in the correctness-path code:
//    hipMemsetAsync(out,0) -> launch_once; the 800MB fillBuffer appears per
//    timed iteration too). Scatter writes only the 5 top-k values per row.
//  * All selection state static-indexed (scratch trap).
#define RT    16
#define NRT   32
#define CTILE 64
#define RSTRD 130      // rowPd stride in doubles (1040 B rows, 16B-aligned)
#define CSTR  132      // colP stride in floats
#define NCT   8

// issue next tile's staging loads into static registers (ordAll must be synced)
#define ISSUE_TILE(CT)                                                        \
    {                                                                         \
        int c0_ = (CT) * CTILE;                                               \
        int jb_ = tid >> 5;                                                   \
        int q4_ = (tid & 31) * 4;                                             \
        p0 = *(const float4*)(ptsB + (size_t)ordAll[min(c0_ + jb_ +  0, BINSZ - 1)] * DIM + q4_); \
        p1 = *(const float4*)(ptsB + (size_t)ordAll[min(c0_ + jb_ +  8, BINSZ - 1)] * DIM + q4_); \
        p2 = *(const float4*)(ptsB + (size_t)ordAll[min(c0_ + jb_ + 16, BINSZ - 1)] * DIM + q4_); \
        p3 = *(const float4*)(ptsB + (size_t)ordAll[min(c0_ + jb_ + 24, BINSZ - 1)] * DIM + q4_); \
        p4 = *(const float4*)(ptsB + (size_t)ordAll[min(c0_ + jb_ + 32, BINSZ - 1)] * DIM + q4_); \
        p5 = *(const float4*)(ptsB + (size_t)ordAll[min(c0_ + jb_ + 40, BINSZ - 1)] * DIM + q4_); \
        p6 = *(const float4*)(ptsB + (size_t)ordAll[min(c0_ + jb_ + 48, BINSZ - 1)] * DIM + q4_); \
        p7 = *(const float4*)(ptsB + (size_t)ordAll[min(c0_ + jb_ + 56, BINSZ - 1)] * DIM + q4_); \
        naCp = na[(size_t)b * NPTS + ordAll[min(c0_ + (tid & 63), BINSZ - 1)]]; \
    }

__launch_bounds__(256, 3)
__global__ void k_chunks(const float* __restrict__ pts, const double* __restrict__ na,
                         const int* __restrict__ order, float* __restrict__ out) {
    __shared__ double rowPd[RT * RSTRD];    // 16640 B
    __shared__ float  colP[CTILE * CSTR];   // 33792 B
    __shared__ double naC[CTILE];           // 512 B
    __shared__ double naRs[RT];             // 128 B
    __shared__ int    ordR[RT];             // 64 B
    __shared__ int    ordAll[BINSZ];        // 2000 B -> 53.1 KB, 3 blocks/CU

    int blk   = blockIdx.x;
    int rt    = blk & (NRT - 1);
    int chunk = blk >> 5;          // 0..19
    int b     = chunk / NBINS;
    int c     = chunk % NBINS;
    int tid   = threadIdx.x;
    int row0  = rt * RT;
    int rowCount = min(RT, BINSZ - row0);   // 16, except last tile: 4

    const int*   ordBase = order + b * NPTS + c * BINSZ;
    const float* ptsB    = pts + (size_t)b * NPTS * DIM;

    // cache this chunk's order slice (kills the per-tile dependent ord loads)
    for (int f = tid; f < BINSZ; f += 256) ordAll[f] = ordBase[f];

    // stage row points as doubles (gathered via order; cvt once per element)
    for (int f = tid; f < rowCount * (DIM / 4); f += 256) {
        int r = f >> 5;
        int q = f & 31;
        int g = ordBase[row0 + r];
        float4 v = *(const float4*)(ptsB + (size_t)g * DIM + q * 4);
        double2 d01; d01.x = (double)v.x; d01.y = (double)v.y;
        double2 d23; d23.x = (double)v.z; d23.y = (double)v.w;
        *(double2*)(&rowPd[r * RSTRD + q * 4 + 0]) = d01;
        *(double2*)(&rowPd[r * RSTRD + q * 4 + 2]) = d23;
    }
    if (tid < rowCount) {
        int g = ordBase[row0 + tid];
        ordR[tid] = g;
        naRs[tid] = na[b * NPTS + g];
    }
    __syncthreads();   // ordAll + rows ready

    int cg  = tid & 15;         // col group: cols cg, cg+16, cg+32, cg+48
    int ks  = (tid >> 4) & 1;   // k-half: dims [64ks, 64ks+64)
    int rg  = tid >> 5;         // 0..7: rows rg, rg+8
    int cgm = tid & 31;         // merge-lane id within half-wave
    const int q0 = ks * 64;

    double naRr0 = (rg     < rowCount) ? naRs[rg]     : 0.;
    double naRr1 = (rg + 8 < rowCount) ? naRs[rg + 8] : 0.;

    // selection key: clamped squared distance (smaller = better); bottom-5,
    // strict < with in-order arrival == (key asc, idx asc), matches ref.
    double tv[2][TOPK];
    int    tl[2][TOPK];
#pragma unroll
    for (int ii = 0; ii < 2; ++ii)
#pragma unroll
        for (int k = 0; k < TOPK; ++k) { tv[ii][k] = DBL_MAX; tl[ii][k] = 0x7fffffff; }

    // prefetch tile 0 into registers
    float4 p0, p1, p2, p3, p4, p5, p6, p7;
    double naCp;
    ISSUE_TILE(0);

    for (int ct = 0; ct < NCT; ++ct) {
        int col0T = ct * CTILE;
        int colCount = min(CTILE, BINSZ - col0T);
        __syncthreads();   // prev tile's readers done before restage

        // write phase: regs (loaded last iteration) -> LDS
        {
            int jb = tid >> 5;
            int q4 = (tid & 31) * 4;
            *(float4*)(&colP[(jb +  0) * CSTR + q4]) = p0;
            *(float4*)(&colP[(jb +  8) * CSTR + q4]) = p1;
            *(float4*)(&colP[(jb + 16) * CSTR + q4]) = p2;
            *(float4*)(&colP[(jb + 24) * CSTR + q4]) = p3;
            *(float4*)(&colP[(jb + 32) * CSTR + q4]) = p4;
            *(float4*)(&colP[(jb + 40) * CSTR + q4]) = p5;
            *(float4*)(&colP[(jb + 48) * CSTR + q4]) = p6;
            *(float4*)(&colP[(jb + 56) * CSTR + q4]) = p7;
            if (tid < CTILE) naC[tid] = naCp;
        }
        __syncthreads();

        // issue next tile's loads now; they complete under this tile's gram
        if (ct + 1 < NCT) ISSUE_TILE(ct + 1);

        // gram: rows {rg, rg+8} x cols {cg,+16,+32,+48}, dims [q0, q0+64)
        double acc00 = 0., acc01 = 0., acc02 = 0., acc03 = 0.;
        double acc10 = 0., acc11 = 0., acc12 = 0., acc13 = 0.;

        for (int q = 0; q < 64; q += 4) {
            const int qq = q0 + q;
            double2 a0lo = *(const double2*)(&rowPd[rg * RSTRD + qq + 0]);
            double2 a0hi = *(const double2*)(&rowPd[rg * RSTRD + qq + 2]);
            double2 a1lo = *(const double2*)(&rowPd[(rg + 8) * RSTRD + qq + 0]);
            double2 a1hi = *(const double2*)(&rowPd[(rg + 8) * RSTRD + qq + 2]);
            float4 f0 = *(const float4*)(&colP[cg * CSTR + qq]);
            float4 f1 = *(const float4*)(&colP[(cg + 16) * CSTR + qq]);
            float4 f2 = *(const float4*)(&colP[(cg + 32) * CSTR + qq]);
            float4 f3 = *(const float4*)(&colP[(cg + 48) * CSTR + qq]);
            double b0x = (double)f0.x, b0y = (double)f0.y, b0z = (double)f0.z, b0w = (double)f0.w;
            double b1x = (double)f1.x, b1y = (double)f1.y, b1z = (double)f1.z, b1w = (double)f1.w;
            double b2x = (double)f2.x, b2y = (double)f2.y, b2z = (double)f2.z, b2w = (double)f2.w;
            double b3x = (double)f3.x, b3y = (double)f3.y, b3z = (double)f3.z, b3w = (double)f3.w;
            acc00 += a0lo.x * b0x + a0lo.y * b0y + a0hi.x * b0z + a0hi.y * b0w;
            acc01 += a0lo.x * b1x + a0lo.y * b1y + a0hi.x * b1z + a0hi.y * b1w;
            acc02 += a0lo.x * b2x + a0lo.y * b2y + a0hi.x * b2z + a0hi.y * b2w;
            acc03 += a0lo.x * b3x + a0lo.y * b3y + a0hi.x * b3z + a0hi.y * b3w;
            acc10 += a1lo.x * b0x + a1lo.y * b0y + a1hi.x * b0z + a1hi.y * b0w;
            acc11 += a1lo.x * b1x + a1lo.y * b1y + a1hi.x * b1z + a1hi.y * b1w;
            acc12 += a1lo.x * b2x + a1lo.y * b2y + a1hi.x * b2z + a1hi.y * b2w;
            acc13 += a1lo.x * b3x + a1lo.y * b3y + a1hi.x * b3z + a1hi.y * b3w;
        }

        // combine k-halves: partner lane = lane^16 (same cg, same rg)
        acc00 += __shfl_xor(acc00, 16, 64);
        acc01 += __shfl_xor(acc01, 16, 64);
        acc02 += __shfl_xor(acc02, 16, 64);
        acc03 += __shfl_xor(acc03, 16, 64);
        acc10 += __shfl_xor(acc10, 16, 64);
        acc11 += __shfl_xor(acc11, 16, 64);
        acc12 += __shfl_xor(acc12, 16, 64);
        acc13 += __shfl_xor(acc13, 16, 64);

        // selection ownership: ks=0 -> cols {cg, cg+16}; ks=1 -> {cg+32, cg+48}
        double selA0 = ks ? acc02 : acc00;   // row rg,   first owned col
        double selA1 = ks ? acc12 : acc10;   // row rg+8, first owned col
        double selB0 = ks ? acc03 : acc01;   // row rg,   second owned col
        double selB1 = ks ? acc13 : acc11;   // row rg+8, second owned col
        int colA = cg + (ks ? 32 : 0);
        int colB = cg + (ks ? 48 : 16);

        if (colA < colCount) {
            int    cl = col0T + colA;
            double nc = naC[colA];
            double cv0 = fmax(naRr0 + nc - 2. * selA0, 1e-6);
            double cv1 = fmax(naRr1 + nc - 2. * selA1, 1e-6);
            int cl0 = cl, cl1 = cl;
#pragma unroll
            for (int k = 0; k < TOPK; ++k) {   // strict <: equal keeps earlier idx
                bool lt0 = (cv0 < tv[0][k]);
                double ov0 = tv[0][k]; int ol0 = tl[0][k];
                if (lt0) { tv[0][k] = cv0; tl[0][k] = cl0; cv0 = ov0; cl0 = ol0; }
                bool lt1 = (cv1 < tv[1][k]);
                double ov1 = tv[1][k]; int ol1 = tl[1][k];
                if (lt1) { tv[1][k] = cv1; tl[1][k] = cl1; cv1 = ov1; cl1 = ol1; }
            }
        }
        if (colB < colCount) {
            int    cl = col0T + colB;
            double nc = naC[colB];
            double cv0 = fmax(naRr0 + nc - 2. * selB0, 1e-6);
            double cv1 = fmax(naRr1 + nc - 2. * selB1, 1e-6);
            int cl0 = cl, cl1 = cl;
#pragma unroll
            for (int k = 0; k < TOPK; ++k) {
                bool lt0 = (cv0 < tv[0][k]);
                double ov0 = tv[0][k]; int ol0 = tl[0][k];
                if (lt0) { tv[0][k] = cv0; tl[0][k] = cl0; cv0 = ov0; cl0 = ol0; }
                bool lt1 = (cv1 < tv[1][k]);
                double ov1 = tv[1][k]; int ol1 = tl[1][k];
                if (lt1) { tv[1][k] = cv1; tl[1][k] = cl1; cv1 = ov1; cl1 = ol1; }
            }
        }
    }

    // merge across the 32 threads of each half-wave (all share rows rg, rg+8;
    // they own disjoint col sets covering 0..499)
#pragma unroll
    for (int m = 1; m < 32; m <<= 1) {
#pragma unroll
        for (int ii = 0; ii < 2; ++ii) {
            double rv[TOPK]; int rl[TOPK];
#pragma unroll
            for (int k = 0; k < TOPK; ++k) {
                rv[k] = __shfl_xor(tv[ii][k], m, 32);
                rl[k] = __shfl_xor(tl[ii][k], m, 32);
            }
#pragma unroll
            for (int k = 0; k < TOPK; ++k) {
                double cv = rv[k]; int cl = rl[k];
#pragma unroll
                for (int s = 0; s < TOPK; ++s) {   // (key asc, idx asc) total order
                    bool better = (cv < tv[ii][s]) || (cv == tv[ii][s] && cl < tl[ii][s]);
                    double ov = tv[ii][s]; int ol = tl[ii][s];
                    if (better) { tv[ii][s] = cv; tl[ii][s] = cl; cv = ov; cl = ol; }
                }
            }
        }
    }

    // scatter: lane cgm==0 of each half-wave writes 2 rows x 5 values.
    // out is pre-zeroed by the harness memset before every launch.
    if (cgm == 0) {
#pragma unroll
        for (int ii = 0; ii < 2; ++ii) {
            int r = rg + 8 * ii;
            if (r < rowCount) {
                int src = ordR[r];
                float* outRow = out + ((size_t)b * NPTS + src) * NPTS;
#pragma unroll
                for (int k = 0; k < TOPK; ++k) {
                    double dist = sqrt(tv[ii][k]);     // tv already clamped
                    double dm   = exp(-0.1 * dist);
                    int dst = ordAll[tl[ii][k]];       // chunk-local -> global
                    outRow[dst] = (float)dm;
                }
            }
        }
    }
}

// ---------------- launch ----------------
extern "C" void kernel_launch(void* const* d_in, const int* in_sizes, int n_in,
                              void* d_out, int out_size, void* d_ws, size_t ws_size,
                              hipStream_t stream) {
    const float* pts = (const float*)d_in[0];   // [2,5000,128]
    const float* rot = (const float*)d_in[1];   // [128,100]
    float* out = (float*)d_out;                 // [2,5000,5000]

    double* na      = (double*)d_ws;                                    // 80000 B
    int*    bin_idx = (int*)((char*)d_ws + 80000);                      // 40000 B
    int*    order   = (int*)((char*)d_ws + 120000);                     // 40000 B

    k_bins<<<(BATCH * NPTS + KB_PTS - 1) / KB_PTS, 256, 0, stream>>>(pts, rot, bin_idx, na);
    k_sort<<<BATCH, 256, 0, stream>>>(bin_idx, order);
    k_chunks<<<BATCH * NBINS * NRT, 256, 0, stream>>>(pts, na, order, out);
}

// Round 11
// 284.345 us; speedup vs baseline: 1.0667x; 1.0246x over previous
//
#include <hip/hip_runtime.h>
#include <cfloat>
#include <math.h>

#define NPTS   5000
#define BATCH  2
#define DIM    128
#define NBINS  10
#define BINSZ  500
#define TOPK   5
#define ROTCOLS 100   // rotations stored [128, 100]; we use first NBINS/2 = 5

// ---------------- Kernel A: bin assignment + squared norms (fp64 acc) -----
// Stays fp64: a single argmax flip vs the np-f64 reference permutes whole
// bins (catastrophic).
#define KB_PTS 64
#define KB_STR 129
__global__ void k_bins(const float* __restrict__ pts, const float* __restrict__ rot,
                       int* __restrict__ bin_idx, double* __restrict__ na) {
    __shared__ float P[KB_PTS * KB_STR];
    __shared__ float rotL[DIM * 5];
    int tid = threadIdx.x;
    for (int f = tid; f < DIM * 5; f += 256)
        rotL[f] = rot[(f / 5) * ROTCOLS + (f % 5)];

    int p0  = blockIdx.x * KB_PTS;
    int npb = min(KB_PTS, BATCH * NPTS - p0);

    for (int f = tid; f < npb * DIM; f += 256) {
        int r = f >> 7, d = f & 127;
        P[r * KB_STR + d] = pts[(size_t)(p0 + r) * DIM + d];
    }
    __syncthreads();

    int p = tid >> 2;    // point within block
    int s = tid & 3;     // dim quarter
    double acc[5] = {0., 0., 0., 0., 0.};
    double sq = 0.;
    const float* row = &P[p * KB_STR + s * 32];
    for (int j = 0; j < 32; ++j) {
        double v = (double)row[j];
        sq += v * v;
        int d = s * 32 + j;
#pragma unroll
        for (int h = 0; h < 5; ++h) acc[h] += v * (double)rotL[d * 5 + h];
    }
#pragma unroll
    for (int m = 1; m < 4; m <<= 1) {
#pragma unroll
        for (int h = 0; h < 5; ++h) acc[h] += __shfl_xor(acc[h], m, 4);
        sq += __shfl_xor(sq, m, 4);
    }
    if (s == 0 && p < npb) {
        double best = acc[0]; int bc = 0;
#pragma unroll
        for (int c = 1; c < NBINS; ++c) {
            double v = (c < 5) ? acc[c] : -acc[c - 5];
            if (v > best) { best = v; bc = c; }
        }
        bin_idx[p0 + p] = bc;
        na[p0 + p] = sq;
    }
}

// ---------------- Kernel B: stable counting sort (== stable argsort) ------
__global__ void k_sort(const int* __restrict__ bin_idx, int* __restrict__ order) {
    const int b = blockIdx.x;
    const int t = threadIdx.x;               // 256 threads
    const int NPT = (NPTS + 255) / 256;      // 20
    int start = t * NPT;
    int end   = min(NPTS, start + NPT);

    int cnt[NBINS];
#pragma unroll
    for (int c = 0; c < NBINS; ++c) cnt[c] = 0;
    for (int i = start; i < end; ++i) {
        int c = bin_idx[b * NPTS + i];
#pragma unroll
        for (int k = 0; k < NBINS; ++k) cnt[k] += (c == k);
    }

    __shared__ int hist[NBINS * 256];
#pragma unroll
    for (int c = 0; c < NBINS; ++c) hist[c * 256 + t] = cnt[c];
    __syncthreads();

    int base = t * NBINS;
    int s = 0;
#pragma unroll
    for (int k = 0; k < NBINS; ++k) s += hist[base + k];
    __shared__ int scan[256];
    scan[t] = s;
    __syncthreads();
    for (int off = 1; off < 256; off <<= 1) {
        int v = (t >= off) ? scan[t - off] : 0;
        __syncthreads();
        scan[t] += v;
        __syncthreads();
    }
    int run = scan[t] - s;
#pragma unroll
    for (int k = 0; k < NBINS; ++k) { int h = hist[base + k]; hist[base + k] = run; run += h; }
    __syncthreads();

    int ofs[NBINS];
#pragma unroll
    for (int c = 0; c < NBINS; ++c) ofs[c] = hist[c * 256 + t];
    for (int i = start; i < end; ++i) {
        int c = bin_idx[b * NPTS + i];
        int pos = 0;
#pragma unroll
        for (int k = 0; k < NBINS; ++k) {
            if (c == k) pos = ofs[k];
            ofs[k] += (c == k);
        }
        order[b * NPTS + pos] = i;
    }
}

// -- Kernel C: k-split 2x4 f64 gram + async-staged tiles + top-5 + zero ----
// FINAL (R10): best verified variant, == R7 (285.7us total, absmax 0.0).
// Evidence ledger (session):
//  * f64 MFMA abandoned (R0-R2): probe outputs match NO layout family on
//    gfx950 -> unusable. Do not revisit without external proof.
//  * R3: -33% LDS reads = zero time change => not LDS-throughput-bound.
//  * R4: f32 gram + 8-wide rank: VALU busy unchanged, duration 2x. Gram
//    FLOPs are NOT dominant; wide-candidate-state is a trap.
//  * R5+R9: zero-fill split out / removed = k_chunks unchanged => embedded
//    zeroing is FREE overlap. Kept embedded (no harness-memset dependence).
//  * R6: occupancy 22->53% (more blocks) = WORSE (+restage). Keep 640 blocks.
//  * R7: ordAll-in-LDS + T14 reg-prefetch staging = 123 -> ~114us (win).
//  * R8: f64 colP staging cut VALU busy 56->47us BUT 2x barrier count =
//    +19us duration. Per-tile barrier overhead ~2.4us dominates: NCT=8.
//  * Residual: ~114us k_chunks = ~56us VALU + barrier-skew/interleave;
//    no single lever moves it. Fixed overhead outside k_chunks ~172us
//    (harness 800MB memset ~125us + k_bins/k_sort/launches ~46us).
//  * All selection state static-indexed (scratch trap).
#define RT    16
#define NRT   32
#define CTILE 64
#define RSTRD 130      // rowPd stride in doubles (1040 B rows, 16B-aligned)
#define CSTR  132      // colP stride in floats
#define NCT   8
#define ROWQ  (NPTS/4)

// issue next tile's staging loads into static registers (ordAll must be synced)
#define ISSUE_TILE(CT)                                                        \
    {                                                                         \
        int c0_ = (CT) * CTILE;                                               \
        int jb_ = tid >> 5;                                                   \
        int q4_ = (tid & 31) * 4;                                             \
        p0 = *(const float4*)(ptsB + (size_t)ordAll[min(c0_ + jb_ +  0, BINSZ - 1)] * DIM + q4_); \
        p1 = *(const float4*)(ptsB + (size_t)ordAll[min(c0_ + jb_ +  8, BINSZ - 1)] * DIM + q4_); \
        p2 = *(const float4*)(ptsB + (size_t)ordAll[min(c0_ + jb_ + 16, BINSZ - 1)] * DIM + q4_); \
        p3 = *(const float4*)(ptsB + (size_t)ordAll[min(c0_ + jb_ + 24, BINSZ - 1)] * DIM + q4_); \
        p4 = *(const float4*)(ptsB + (size_t)ordAll[min(c0_ + jb_ + 32, BINSZ - 1)] * DIM + q4_); \
        p5 = *(const float4*)(ptsB + (size_t)ordAll[min(c0_ + jb_ + 40, BINSZ - 1)] * DIM + q4_); \
        p6 = *(const float4*)(ptsB + (size_t)ordAll[min(c0_ + jb_ + 48, BINSZ - 1)] * DIM + q4_); \
        p7 = *(const float4*)(ptsB + (size_t)ordAll[min(c0_ + jb_ + 56, BINSZ - 1)] * DIM + q4_); \
        naCp = na[(size_t)b * NPTS + ordAll[min(c0_ + (tid & 63), BINSZ - 1)]]; \
    }

__launch_bounds__(256, 3)
__global__ void k_chunks(const float* __restrict__ pts, const double* __restrict__ na,
                         const int* __restrict__ order, float* __restrict__ out) {
    __shared__ double rowPd[RT * RSTRD];    // 16640 B
    __shared__ float  colP[CTILE * CSTR];   // 33792 B
    __shared__ double naC[CTILE];           // 512 B
    __shared__ double naRs[RT];             // 128 B
    __shared__ int    ordR[RT];             // 64 B
    __shared__ int    ordAll[BINSZ];        // 2000 B -> 53.1 KB, 3 blocks/CU

    int blk   = blockIdx.x;
    int rt    = blk & (NRT - 1);
    int chunk = blk >> 5;          // 0..19
    int b     = chunk / NBINS;
    int c     = chunk % NBINS;
    int tid   = threadIdx.x;
    int row0  = rt * RT;
    int rowCount = min(RT, BINSZ - row0);   // 16, except last tile: 4

    const int*   ordBase = order + b * NPTS + c * BINSZ;
    const float* ptsB    = pts + (size_t)b * NPTS * DIM;

    // cache this chunk's order slice (kills the per-tile dependent ord loads)
    for (int f = tid; f < BINSZ; f += 256) ordAll[f] = ordBase[f];

    // stage row points as doubles (gathered via order; cvt once per element)
    for (int f = tid; f < rowCount * (DIM / 4); f += 256) {
        int r = f >> 5;
        int q = f & 31;
        int g = ordBase[row0 + r];
        float4 v = *(const float4*)(ptsB + (size_t)g * DIM + q * 4);
        double2 d01; d01.x = (double)v.x; d01.y = (double)v.y;
        double2 d23; d23.x = (double)v.z; d23.y = (double)v.w;
        *(double2*)(&rowPd[r * RSTRD + q * 4 + 0]) = d01;
        *(double2*)(&rowPd[r * RSTRD + q * 4 + 2]) = d23;
    }
    if (tid < rowCount) {
        int g = ordBase[row0 + tid];
        ordR[tid] = g;
        naRs[tid] = na[b * NPTS + g];
    }
    __syncthreads();   // ordAll + rows ready

    int cg  = tid & 15;         // col group: cols cg, cg+16, cg+32, cg+48
    int ks  = (tid >> 4) & 1;   // k-half: dims [64ks, 64ks+64)
    int rg  = tid >> 5;         // 0..7: rows rg, rg+8
    int cgm = tid & 31;         // merge-lane id within half-wave
    const int q0 = ks * 64;

    double naRr0 = (rg     < rowCount) ? naRs[rg]     : 0.;
    double naRr1 = (rg + 8 < rowCount) ? naRs[rg + 8] : 0.;

    // selection key: clamped squared distance (smaller = better); bottom-5,
    // strict < with in-order arrival == (key asc, idx asc), matches ref.
    double tv[2][TOPK];
    int    tl[2][TOPK];
#pragma unroll
    for (int ii = 0; ii < 2; ++ii)
#pragma unroll
        for (int k = 0; k < TOPK; ++k) { tv[ii][k] = DBL_MAX; tl[ii][k] = 0x7fffffff; }

    const int totalZ = rowCount * ROWQ;

    // prefetch tile 0 into registers
    float4 p0, p1, p2, p3, p4, p5, p6, p7;
    double naCp;
    ISSUE_TILE(0);

    for (int ct = 0; ct < NCT; ++ct) {
        int col0T = ct * CTILE;
        int colCount = min(CTILE, BINSZ - col0T);
        __syncthreads();   // prev tile's readers done before restage

        // write phase: regs (loaded last iteration) -> LDS
        {
            int jb = tid >> 5;
            int q4 = (tid & 31) * 4;
            *(float4*)(&colP[(jb +  0) * CSTR + q4]) = p0;
            *(float4*)(&colP[(jb +  8) * CSTR + q4]) = p1;
            *(float4*)(&colP[(jb + 16) * CSTR + q4]) = p2;
            *(float4*)(&colP[(jb + 24) * CSTR + q4]) = p3;
            *(float4*)(&colP[(jb + 32) * CSTR + q4]) = p4;
            *(float4*)(&colP[(jb + 40) * CSTR + q4]) = p5;
            *(float4*)(&colP[(jb + 48) * CSTR + q4]) = p6;
            *(float4*)(&colP[(jb + 56) * CSTR + q4]) = p7;
            if (tid < CTILE) naC[tid] = naCp;
        }
        __syncthreads();

        // issue next tile's loads now; they complete under this tile's gram
        if (ct + 1 < NCT) ISSUE_TILE(ct + 1);

        // zero-fill slice ct: stores drain during this tile's gram compute
        {
            float4 z = make_float4(0.f, 0.f, 0.f, 0.f);
            int z0 = (ct * totalZ) / NCT, z1 = ((ct + 1) * totalZ) / NCT;
            for (int f = z0 + tid; f < z1; f += 256) {
                int r = f / ROWQ;
                int q = f - r * ROWQ;
                float* outRow = out + ((size_t)b * NPTS + ordR[r]) * NPTS;
                *(float4*)(outRow + 4 * q) = z;
            }
        }

        // gram: rows {rg, rg+8} x cols {cg,+16,+32,+48}, dims [q0, q0+64)
        double acc00 = 0., acc01 = 0., acc02 = 0., acc03 = 0.;
        double acc10 = 0., acc11 = 0., acc12 = 0., acc13 = 0.;

        for (int q = 0; q < 64; q += 4) {
            const int qq = q0 + q;
            double2 a0lo = *(const double2*)(&rowPd[rg * RSTRD + qq + 0]);
            double2 a0hi = *(const double2*)(&rowPd[rg * RSTRD + qq + 2]);
            double2 a1lo = *(const double2*)(&rowPd[(rg + 8) * RSTRD + qq + 0]);
            double2 a1hi = *(const double2*)(&rowPd[(rg + 8) * RSTRD + qq + 2]);
            float4 f0 = *(const float4*)(&colP[cg * CSTR + qq]);
            float4 f1 = *(const float4*)(&colP[(cg + 16) * CSTR + qq]);
            float4 f2 = *(const float4*)(&colP[(cg + 32) * CSTR + qq]);
            float4 f3 = *(const float4*)(&colP[(cg + 48) * CSTR + qq]);
            double b0x = (double)f0.x, b0y = (double)f0.y, b0z = (double)f0.z, b0w = (double)f0.w;
            double b1x = (double)f1.x, b1y = (double)f1.y, b1z = (double)f1.z, b1w = (double)f1.w;
            double b2x = (double)f2.x, b2y = (double)f2.y, b2z = (double)f2.z, b2w = (double)f2.w;
            double b3x = (double)f3.x, b3y = (double)f3.y, b3z = (double)f3.z, b3w = (double)f3.w;
            acc00 += a0lo.x * b0x + a0lo.y * b0y + a0hi.x * b0z + a0hi.y * b0w;
            acc01 += a0lo.x * b1x + a0lo.y * b1y + a0hi.x * b1z + a0hi.y * b1w;
            acc02 += a0lo.x * b2x + a0lo.y * b2y + a0hi.x * b2z + a0hi.y * b2w;
            acc03 += a0lo.x * b3x + a0lo.y * b3y + a0hi.x * b3z + a0hi.y * b3w;
            acc10 += a1lo.x * b0x + a1lo.y * b0y + a1hi.x * b0z + a1hi.y * b0w;
            acc11 += a1lo.x * b1x + a1lo.y * b1y + a1hi.x * b1z + a1hi.y * b1w;
            acc12 += a1lo.x * b2x + a1lo.y * b2y + a1hi.x * b2z + a1hi.y * b2w;
            acc13 += a1lo.x * b3x + a1lo.y * b3y + a1hi.x * b3z + a1hi.y * b3w;
        }

        // combine k-halves: partner lane = lane^16 (same cg, same rg)
        acc00 += __shfl_xor(acc00, 16, 64);
        acc01 += __shfl_xor(acc01, 16, 64);
        acc02 += __shfl_xor(acc02, 16, 64);
        acc03 += __shfl_xor(acc03, 16, 64);
        acc10 += __shfl_xor(acc10, 16, 64);
        acc11 += __shfl_xor(acc11, 16, 64);
        acc12 += __shfl_xor(acc12, 16, 64);
        acc13 += __shfl_xor(acc13, 16, 64);

        // selection ownership: ks=0 -> cols {cg, cg+16}; ks=1 -> {cg+32, cg+48}
        double selA0 = ks ? acc02 : acc00;   // row rg,   first owned col
        double selA1 = ks ? acc12 : acc10;   // row rg+8, first owned col
        double selB0 = ks ? acc03 : acc01;   // row rg,   second owned col
        double selB1 = ks ? acc13 : acc11;   // row rg+8, second owned col
        int colA = cg + (ks ? 32 : 0);
        int colB = cg + (ks ? 48 : 16);

        if (colA < colCount) {
            int    cl = col0T + colA;
            double nc = naC[colA];
            double cv0 = fmax(naRr0 + nc - 2. * selA0, 1e-6);
            double cv1 = fmax(naRr1 + nc - 2. * selA1, 1e-6);
            int cl0 = cl, cl1 = cl;
#pragma unroll
            for (int k = 0; k < TOPK; ++k) {   // strict <: equal keeps earlier idx
                bool lt0 = (cv0 < tv[0][k]);
                double ov0 = tv[0][k]; int ol0 = tl[0][k];
                if (lt0) { tv[0][k] = cv0; tl[0][k] = cl0; cv0 = ov0; cl0 = ol0; }
                bool lt1 = (cv1 < tv[1][k]);
                double ov1 = tv[1][k]; int ol1 = tl[1][k];
                if (lt1) { tv[1][k] = cv1; tl[1][k] = cl1; cv1 = ov1; cl1 = ol1; }
            }
        }
        if (colB < colCount) {
            int    cl = col0T + colB;
            double nc = naC[colB];
            double cv0 = fmax(naRr0 + nc - 2. * selB0, 1e-6);
            double cv1 = fmax(naRr1 + nc - 2. * selB1, 1e-6);
            int cl0 = cl, cl1 = cl;
#pragma unroll
            for (int k = 0; k < TOPK; ++k) {
                bool lt0 = (cv0 < tv[0][k]);
                double ov0 = tv[0][k]; int ol0 = tl[0][k];
                if (lt0) { tv[0][k] = cv0; tl[0][k] = cl0; cv0 = ov0; cl0 = ol0; }
                bool lt1 = (cv1 < tv[1][k]);
                double ov1 = tv[1][k]; int ol1 = tl[1][k];
                if (lt1) { tv[1][k] = cv1; tl[1][k] = cl1; cv1 = ov1; cl1 = ol1; }
            }
        }
    }

    // merge across the 32 threads of each half-wave (all share rows rg, rg+8;
    // they own disjoint col sets covering 0..499)
#pragma unroll
    for (int m = 1; m < 32; m <<= 1) {
#pragma unroll
        for (int ii = 0; ii < 2; ++ii) {
            double rv[TOPK]; int rl[TOPK];
#pragma unroll
            for (int k = 0; k < TOPK; ++k) {
                rv[k] = __shfl_xor(tv[ii][k], m, 32);
                rl[k] = __shfl_xor(tl[ii][k], m, 32);
            }
#pragma unroll
            for (int k = 0; k < TOPK; ++k) {
                double cv = rv[k]; int cl = rl[k];
#pragma unroll
                for (int s = 0; s < TOPK; ++s) {   // (key asc, idx asc) total order
                    bool better = (cv < tv[ii][s]) || (cv == tv[ii][s] && cl < tl[ii][s]);
                    double ov = tv[ii][s]; int ol = tl[ii][s];
                    if (better) { tv[ii][s] = cv; tl[ii][s] = cl; cv = ov; cl = ol; }
                }
            }
        }
    }

    __syncthreads();   // drain last zero slice before value scatter

    // scatter: lane cgm==0 of each half-wave writes 2 rows x 5 values
    if (cgm == 0) {
#pragma unroll
        for (int ii = 0; ii < 2; ++ii) {
            int r = rg + 8 * ii;
            if (r < rowCount) {
                int src = ordR[r];
                float* outRow = out + ((size_t)b * NPTS + src) * NPTS;
#pragma unroll
                for (int k = 0; k < TOPK; ++k) {
                    double dist = sqrt(tv[ii][k]);     // tv already clamped
                    double dm   = exp(-0.1 * dist);
                    int dst = ordAll[tl[ii][k]];       // chunk-local -> global
                    outRow[dst] = (float)dm;
                }
            }
        }
    }
}

// ---------------- launch ----------------
extern "C" void kernel_launch(void* const* d_in, const int* in_sizes, int n_in,
                              void* d_out, int out_size, void* d_ws, size_t ws_size,
                              hipStream_t stream) {
    const float* pts = (const float*)d_in[0];   // [2,5000,128]
    const float* rot = (const float*)d_in[1];   // [128,100]
    float* out = (float*)d_out;                 // [2,5000,5000]

    double* na      = (double*)d_ws;                                    // 80000 B
    int*    bin_idx = (int*)((char*)d_ws + 80000);                      // 40000 B
    int*    order   = (int*)((char*)d_ws + 120000);                     // 40000 B

    k_bins<<<(BATCH * NPTS + KB_PTS - 1) / KB_PTS, 256, 0, stream>>>(pts, rot, bin_idx, na);
    k_sort<<<BATCH, 256, 0, stream>>>(bin_idx, order);
    k_chunks<<<BATCH * NBINS * NRT, 256, 0, stream>>>(pts, na, order, out);
}